// Round 1
// baseline (325.627 us; speedup 1.0000x reference)
//
#include <hip/hip_runtime.h>

#define NB 8
#define NA 9
#define HH 128
#define WW 128
#define NCELL (HH * WW)      // 16384
#define NTOT (NCELL * NA)    // 147456
#define PRE_K 2000
#define POST_K 300
#define CAP 4096
#define NMS_TH 0.7f

// anchor widths/heights (exact integers); all anchor centers are 16*(w,h)+8
__constant__ float c_aw[NA] = {184.f, 368.f, 736.f, 128.f, 256.f, 512.f, 88.f, 176.f, 352.f};
__constant__ float c_ah[NA] = {96.f, 192.f, 384.f, 128.f, 256.f, 512.f, 176.f, 352.f, 704.f};

__device__ __forceinline__ unsigned int sortable(float s) {
    unsigned int u = __float_as_uint(s);
    return (u & 0x80000000u) ? ~u : (u | 0x80000000u);
}

// ---------------- radix-select: histogram pass ----------------
// grid (36, B), block 256; each block covers 4096 contiguous elems of
// channel-major layout t = a*16384 + h*128 + w (order irrelevant for hist)
__global__ void hist_kernel(const float* __restrict__ scores,
                            unsigned int* __restrict__ hist,
                            const uint2* __restrict__ state, int pass) {
    __shared__ unsigned int h[256];
    int b = blockIdx.y;
    h[threadIdx.x] = 0;
    __syncthreads();
    unsigned int prefix = 0;
    if (pass > 0) prefix = state[b].x;
    const float* sp = scores + (size_t)b * 18 * NCELL + (size_t)NA * NCELL;
    int base = blockIdx.x * 4096;
    for (int e = 0; e < 16; ++e) {
        int t = base + e * 256 + threadIdx.x;  // t < 147456 always
        unsigned int u = sortable(sp[t]);
        bool ok = (pass == 0) || ((u >> (32 - 8 * pass)) == prefix);
        if (ok) atomicAdd(&h[(u >> (24 - 8 * pass)) & 255u], 1u);
    }
    __syncthreads();
    atomicAdd(&hist[((size_t)pass * NB + b) * 256 + threadIdx.x], h[threadIdx.x]);
}

// ---------------- radix-select: pick digit ----------------
__global__ void select_kernel(const unsigned int* __restrict__ hist,
                              uint2* __restrict__ state, int pass) {
    if (threadIdx.x != 0) return;
    int b = blockIdx.x;
    const unsigned int* h = hist + ((size_t)pass * NB + b) * 256;
    unsigned int prefix;
    int need;
    if (pass == 0) { prefix = 0u; need = PRE_K; }
    else { uint2 st = state[b]; prefix = st.x; need = (int)st.y; }
    int cum = 0, d = 0;
    for (int dd = 255; dd >= 0; --dd) {
        int c = (int)h[dd];
        if (cum + c >= need) { d = dd; break; }
        cum += c;
    }
    state[b] = make_uint2((prefix << 8) | (unsigned int)d, (unsigned int)(need - cum));
}

// ---------------- gather candidates >= pivot ----------------
__global__ void gather_kernel(const float* __restrict__ scores,
                              const uint2* __restrict__ state,
                              int* __restrict__ cnt,
                              unsigned long long* __restrict__ buf) {
    int b = blockIdx.y;
    unsigned int P = state[b].x;
    const float* sp = scores + (size_t)b * 18 * NCELL + (size_t)NA * NCELL;
    int base = blockIdx.x * 4096;
    for (int e = 0; e < 16; ++e) {
        int t = base + e * 256 + threadIdx.x;
        unsigned int u = sortable(sp[t]);
        if (u >= P) {
            int a = t >> 14;         // t = a*16384 + rem
            int rem = t & 16383;
            unsigned int i = (unsigned int)rem * 9u + (unsigned int)a;  // original flat index
            int pos = atomicAdd(&cnt[b], 1);
            if (pos < CAP)
                buf[(size_t)b * CAP + pos] =
                    ((unsigned long long)u << 32) | (unsigned long long)(0xFFFFFFFFu - i);
        }
    }
}

// ---------------- per-batch bitonic sort (desc), emit top-2000 indices ----------------
__global__ __launch_bounds__(1024) void sort_kernel(const unsigned long long* __restrict__ buf,
                                                    const int* __restrict__ cnt,
                                                    unsigned int* __restrict__ topidx) {
    __shared__ unsigned long long s[CAP];
    int b = blockIdx.x;
    int n = min(cnt[b], CAP);
    for (int t = threadIdx.x; t < CAP; t += 1024)
        s[t] = (t < n) ? buf[(size_t)b * CAP + t] : 0ULL;
    __syncthreads();
    for (int k = 2; k <= CAP; k <<= 1) {
        for (int j = k >> 1; j > 0; j >>= 1) {
            for (int t = threadIdx.x; t < CAP; t += 1024) {
                int ixj = t ^ j;
                if (ixj > t) {
                    unsigned long long x = s[t], y = s[ixj];
                    bool desc = ((t & k) == 0);
                    if (desc ? (x < y) : (x > y)) { s[t] = y; s[ixj] = x; }
                }
            }
            __syncthreads();
        }
    }
    for (int r = threadIdx.x; r < PRE_K; r += 1024)
        topidx[(size_t)b * PRE_K + r] = 0xFFFFFFFFu - (unsigned int)(s[r] & 0xFFFFFFFFu);
}

// ---------------- decode + clip boxes for the selected 2000 ----------------
__global__ void boxes_kernel(const unsigned int* __restrict__ topidx,
                             const float* __restrict__ deltas,
                             const float* __restrict__ im_info,
                             float4* __restrict__ boxes) {
    int gid = blockIdx.x * 256 + threadIdx.x;
    if (gid >= NB * PRE_K) return;
    int b = gid / PRE_K;
    unsigned int i = topidx[gid];
    unsigned int cell = i / 9u;
    unsigned int a = i - cell * 9u;
    int wx = (int)(cell & 127u), hy = (int)(cell >> 7);
    const float* dp = deltas + (size_t)b * 36 * NCELL + (size_t)(4u * a) * NCELL +
                      (size_t)hy * WW + wx;
    float dx = dp[0];
    float dy = dp[NCELL];
    float dw = dp[2 * NCELL];
    float dh = dp[3 * NCELL];
    float W_ = c_aw[a], H_ = c_ah[a];
    float cx = (float)(16 * wx + 8), cy = (float)(16 * hy + 8);
    // match reference op-by-op in f32 (no contraction); exp via double (correctly rounded)
    float px = __fadd_rn(__fmul_rn(dx, W_), cx);
    float py = __fadd_rn(__fmul_rn(dy, H_), cy);
    float pw = __fmul_rn((float)exp((double)dw), W_);
    float ph = __fmul_rn((float)exp((double)dh), H_);
    float hw = __fmul_rn(0.5f, pw), hh = __fmul_rn(0.5f, ph);
    float x1 = __fsub_rn(px, hw), y1 = __fsub_rn(py, hh);
    float x2 = __fadd_rn(px, hw), y2 = __fadd_rn(py, hh);
    float maxx = __fsub_rn(im_info[b * 3 + 1], 1.0f);
    float maxy = __fsub_rn(im_info[b * 3 + 0], 1.0f);
    x1 = fminf(fmaxf(x1, 0.0f), maxx);
    y1 = fminf(fmaxf(y1, 0.0f), maxy);
    x2 = fminf(fmaxf(x2, 0.0f), maxx);
    y2 = fminf(fmaxf(y2, 0.0f), maxy);
    boxes[gid] = make_float4(x1, y1, x2, y2);
}

// ---------------- NMS suppression bitmask ----------------
// grid (32 colBlocks, 32 rowBlocks, B), block 64
__global__ void mask_kernel(const float4* __restrict__ boxes,
                            unsigned long long* __restrict__ mask) {
    int colB = blockIdx.x, rowB = blockIdx.y, b = blockIdx.z;
    if (colB < rowB) return;
    __shared__ float4 cb[64];
    int t = threadIdx.x;
    int j0 = colB * 64;
    cb[t] = (j0 + t < PRE_K) ? boxes[(size_t)b * PRE_K + j0 + t] : make_float4(0.f, 0.f, -1.f, -1.f);
    __syncthreads();
    int i = rowB * 64 + t;
    if (i >= PRE_K) return;
    float4 mb = boxes[(size_t)b * PRE_K + i];
    float aarea = __fmul_rn(__fsub_rn(mb.z, mb.x), __fsub_rn(mb.w, mb.y));
    unsigned long long m = 0ULL;
    for (int jj = 0; jj < 64; ++jj) {
        int j = j0 + jj;
        if (j > i && j < PRE_K) {
            float4 c = cb[jj];
            float xx1 = fmaxf(mb.x, c.x), yy1 = fmaxf(mb.y, c.y);
            float xx2 = fminf(mb.z, c.z), yy2 = fminf(mb.w, c.w);
            float iw = fmaxf(__fsub_rn(xx2, xx1), 0.0f);
            float ih = fmaxf(__fsub_rn(yy2, yy1), 0.0f);
            float inter = __fmul_rn(iw, ih);
            float barea = __fmul_rn(__fsub_rn(c.z, c.x), __fsub_rn(c.w, c.y));
            float denom = __fadd_rn(__fsub_rn(__fadd_rn(aarea, barea), inter), 1e-9f);
            float iou = __fdiv_rn(inter, denom);
            if (iou > NMS_TH) m |= (1ULL << jj);
        }
    }
    mask[((size_t)(b * PRE_K + i)) * 32 + colB] = m;
}

// ---------------- serial greedy scan + output ----------------
#define CH 8
#define NCH (PRE_K / CH)  // 250

#define LOAD_CHUNK(BUF, C)                                               \
    _Pragma("unroll") for (int t = 0; t < CH; ++t) BUF[t] =              \
        act ? mrow[((size_t)((C) * CH + t)) * 32 + lane] : 0ULL;

#define PROCESS_CHUNK(BUF, CBASE)                                        \
    _Pragma("unroll") for (int t = 0; t < CH; ++t) {                     \
        int i = (CBASE) + t;                                             \
        int w = i >> 6;                                                  \
        unsigned long long rw = __shfl(remv, w, 64);                     \
        if (!((rw >> (i & 63)) & 1ULL)) {                                \
            if (lane == 0 && cnt < POST_K) keeplist[cnt] = i;            \
            cnt++;                                                       \
            if (lane >= w) remv |= BUF[t];                               \
        }                                                                \
    }

__global__ void scan_kernel(const unsigned long long* __restrict__ mask,
                            const float4* __restrict__ boxes,
                            float* __restrict__ out) {
    int b = blockIdx.x;
    int lane = threadIdx.x;
    const unsigned long long* mrow = mask + (size_t)b * PRE_K * 32;
    __shared__ int keeplist[POST_K];
    bool act = lane < 32;
    unsigned long long remv = 0ULL;
    int cnt = 0;
    unsigned long long bufA[CH], bufB[CH];
    LOAD_CHUNK(bufA, 0)
    LOAD_CHUNK(bufB, 1)
    for (int c = 0; c < NCH; c += 2) {
        PROCESS_CHUNK(bufA, c * CH)
        if (cnt >= POST_K) break;
        if (c + 2 < NCH) { LOAD_CHUNK(bufA, c + 2) }
        PROCESS_CHUNK(bufB, (c + 1) * CH)
        if (cnt >= POST_K) break;
        if (c + 3 < NCH) { LOAD_CHUNK(bufB, c + 3) }
    }
    __syncthreads();
    int K = min(cnt, POST_K);
    const float4* bb = boxes + (size_t)b * PRE_K;
    for (int r = lane; r < POST_K; r += 64) {
        float4 v = make_float4(0.f, 0.f, 0.f, 0.f);
        if (r < K) v = bb[keeplist[r]];
        float* o = out + ((size_t)b * POST_K + r) * 5;
        o[0] = (float)b;
        o[1] = v.x;
        o[2] = v.y;
        o[3] = v.z;
        o[4] = v.w;
    }
}

// ---------------- launcher ----------------
extern "C" void kernel_launch(void* const* d_in, const int* in_sizes, int n_in,
                              void* d_out, int out_size, void* d_ws, size_t ws_size,
                              hipStream_t stream) {
    const float* scores = (const float*)d_in[0];
    const float* deltas = (const float*)d_in[1];
    const float* im_info = (const float*)d_in[2];
    float* out = (float*)d_out;
    char* ws = (char*)d_ws;

    // workspace layout (bytes)
    unsigned int* hist = (unsigned int*)(ws + 0);            // 4*8*256*4 = 32768
    int* cnt = (int*)(ws + 32768);                           // 32
    uint2* state = (uint2*)(ws + 32800);                     // 64
    unsigned long long* buf = (unsigned long long*)(ws + 32864);   // 8*4096*8 = 262144
    unsigned int* topidx = (unsigned int*)(ws + 295008);     // 8*2000*4 = 64000
    float4* props = (float4*)(ws + 359008);                  // 8*2000*16 = 256000
    unsigned long long* mask = (unsigned long long*)(ws + 615008); // 8*2000*32*8 = 4096000
    // total ≈ 4.71 MB

    hipMemsetAsync(ws, 0, 32800, stream);  // hist + cnt
    for (int p = 0; p < 4; ++p) {
        hipLaunchKernelGGL(hist_kernel, dim3(36, NB), dim3(256), 0, stream, scores, hist, state, p);
        hipLaunchKernelGGL(select_kernel, dim3(NB), dim3(64), 0, stream, hist, state, p);
    }
    hipLaunchKernelGGL(gather_kernel, dim3(36, NB), dim3(256), 0, stream, scores, state, cnt, buf);
    hipLaunchKernelGGL(sort_kernel, dim3(NB), dim3(1024), 0, stream, buf, cnt, topidx);
    hipLaunchKernelGGL(boxes_kernel, dim3((NB * PRE_K + 255) / 256), dim3(256), 0, stream,
                       topidx, deltas, im_info, props);
    hipLaunchKernelGGL(mask_kernel, dim3(32, 32, NB), dim3(64), 0, stream, props, mask);
    hipLaunchKernelGGL(scan_kernel, dim3(NB), dim3(64), 0, stream, mask, props, out);
}

// Round 2
// 220.161 us; speedup vs baseline: 1.4790x; 1.4790x over previous
//
#include <hip/hip_runtime.h>

#define NB 8
#define NA 9
#define HH 128
#define WW 128
#define NCELL (HH * WW)      // 16384
#define NTOT (NCELL * NA)    // 147456
#define PRE_K 2000
#define POST_K 300
#define CAP 4096
#define TPB 1024
#define NMS_TH 0.7f

// anchor widths/heights (exact integers); all anchor centers are 16*(w,h)+8
__constant__ float c_aw[NA] = {184.f, 368.f, 736.f, 128.f, 256.f, 512.f, 88.f, 176.f, 352.f};
__constant__ float c_ah[NA] = {96.f, 192.f, 384.f, 128.f, 256.f, 512.f, 176.f, 352.f, 704.f};

__device__ __forceinline__ unsigned int sortable(float s) {
    unsigned int u = __float_as_uint(s);
    return (u & 0x80000000u) ? ~u : (u | 0x80000000u);
}

// suffix-scan 256 bins, pick highest digit d with count(>=d) >= need; update
// s_pref (<<8 | d) and s_need (need - count(>d)). Must be called by ALL threads.
__device__ __forceinline__ void select256(unsigned int* hist, unsigned int* scanb,
                                          unsigned int* s_pref, int* s_need, int tid) {
    if (tid < 256) scanb[tid] = hist[tid];
    __syncthreads();
#pragma unroll
    for (int off = 1; off < 256; off <<= 1) {
        unsigned int v = 0;
        if (tid < 256 && tid + off < 256) v = scanb[tid + off];
        __syncthreads();
        if (tid < 256) scanb[tid] += v;
        __syncthreads();
    }
    // scanb[d] = count of elems with digit >= d (non-increasing in d)
    int need = *s_need;
    unsigned int oldpref = *s_pref;
    if (tid < 256) {
        bool sel = (scanb[tid] >= (unsigned int)need) &&
                   (tid == 255 || scanb[tid + 1] < (unsigned int)need);
        if (sel) {
            *s_pref = (oldpref << 8) | (unsigned int)tid;
            *s_need = need - ((tid == 255) ? 0 : (int)scanb[tid + 1]);
        }
    }
    __syncthreads();
}

// ---------- fused per-batch: 2-pass radix select + gather + bitonic sort + decode ----------
__global__ __launch_bounds__(1024) void topk_kernel(const float* __restrict__ scores,
                                                    const float* __restrict__ deltas,
                                                    const float* __restrict__ im_info,
                                                    float4* __restrict__ props) {
    int b = blockIdx.x;
    int tid = threadIdx.x;
    const float* sp = scores + (size_t)b * 18 * NCELL + (size_t)NA * NCELL;
    const float4* sp4 = (const float4*)sp;

    __shared__ unsigned int hist[256];
    __shared__ unsigned int scanb[256];
    __shared__ unsigned int s_pref;
    __shared__ int s_need;
    __shared__ int s_cnt;
    __shared__ unsigned long long buf[CAP];

    if (tid == 0) { s_pref = 0u; s_need = PRE_K; s_cnt = 0; }
    if (tid < 256) hist[tid] = 0;
    __syncthreads();

    // pass 0: bits [31:24]
    for (int t = tid; t < NTOT / 4; t += TPB) {
        float4 v = sp4[t];
        atomicAdd(&hist[sortable(v.x) >> 24], 1u);
        atomicAdd(&hist[sortable(v.y) >> 24], 1u);
        atomicAdd(&hist[sortable(v.z) >> 24], 1u);
        atomicAdd(&hist[sortable(v.w) >> 24], 1u);
    }
    __syncthreads();
    select256(hist, scanb, &s_pref, &s_need, tid);

    // pass 1: bits [23:16] within selected top-8-bit bin
    if (tid < 256) hist[tid] = 0;
    __syncthreads();
    unsigned int pref0 = s_pref;
    for (int t = tid; t < NTOT / 4; t += TPB) {
        float4 v = sp4[t];
        unsigned int u;
        u = sortable(v.x); if ((u >> 24) == pref0) atomicAdd(&hist[(u >> 16) & 255u], 1u);
        u = sortable(v.y); if ((u >> 24) == pref0) atomicAdd(&hist[(u >> 16) & 255u], 1u);
        u = sortable(v.z); if ((u >> 24) == pref0) atomicAdd(&hist[(u >> 16) & 255u], 1u);
        u = sortable(v.w); if ((u >> 24) == pref0) atomicAdd(&hist[(u >> 16) & 255u], 1u);
    }
    __syncthreads();
    select256(hist, scanb, &s_pref, &s_need, tid);

    // gather all candidates with u >= pivot (16-bit prefix) into LDS
    unsigned int P = s_pref << 16;
    for (int t = tid; t < NTOT / 4; t += TPB) {
        float4 v = sp4[t];
        float e[4] = {v.x, v.y, v.z, v.w};
#pragma unroll
        for (int j = 0; j < 4; ++j) {
            unsigned int u = sortable(e[j]);
            if (u >= P) {
                int idx4 = t * 4 + j;              // = a*16384 + cell (channel-major)
                int a = idx4 >> 14;
                int cell = idx4 & 16383;
                unsigned int i = (unsigned int)cell * 9u + (unsigned int)a;  // (h,w,a) flat order
                int pos = atomicAdd(&s_cnt, 1);
                if (pos < CAP)
                    buf[pos] = ((unsigned long long)u << 32) |
                               (unsigned long long)(0xFFFFFFFFu - i);
            }
        }
    }
    __syncthreads();
    int n = min(s_cnt, CAP);
    int SZ = (n <= 2048) ? 2048 : CAP;
    for (int t = tid; t < SZ; t += TPB)
        if (t >= n) buf[t] = 0ULL;
    __syncthreads();

    // bitonic sort descending by (sortable_score, ~index)
    for (int k = 2; k <= SZ; k <<= 1) {
        for (int j = k >> 1; j > 0; j >>= 1) {
            for (int t = tid; t < SZ; t += TPB) {
                int ixj = t ^ j;
                if (ixj > t) {
                    unsigned long long x = buf[t], y = buf[ixj];
                    if (((t & k) == 0) ? (x < y) : (x > y)) { buf[t] = y; buf[ixj] = x; }
                }
            }
            __syncthreads();
        }
    }

    // decode + clip boxes for the top-2000 (numerics identical to passing version)
    float maxx = __fsub_rn(im_info[b * 3 + 1], 1.0f);
    float maxy = __fsub_rn(im_info[b * 3 + 0], 1.0f);
    const float* dbase = deltas + (size_t)b * 36 * NCELL;
    for (int r = tid; r < PRE_K; r += TPB) {
        unsigned int i = 0xFFFFFFFFu - (unsigned int)(buf[r] & 0xFFFFFFFFu);
        unsigned int cell = i / 9u;
        unsigned int a = i - cell * 9u;
        int wx = (int)(cell & 127u), hy = (int)(cell >> 7);
        const float* dp = dbase + (size_t)(4u * a) * NCELL + (size_t)hy * WW + wx;
        float dx = dp[0];
        float dy = dp[NCELL];
        float dw = dp[2 * NCELL];
        float dh = dp[3 * NCELL];
        float W_ = c_aw[a], H_ = c_ah[a];
        float cx = (float)(16 * wx + 8), cy = (float)(16 * hy + 8);
        float px = __fadd_rn(__fmul_rn(dx, W_), cx);
        float py = __fadd_rn(__fmul_rn(dy, H_), cy);
        float pw = __fmul_rn((float)exp((double)dw), W_);
        float ph = __fmul_rn((float)exp((double)dh), H_);
        float hw = __fmul_rn(0.5f, pw), hh = __fmul_rn(0.5f, ph);
        float x1 = __fsub_rn(px, hw), y1 = __fsub_rn(py, hh);
        float x2 = __fadd_rn(px, hw), y2 = __fadd_rn(py, hh);
        x1 = fminf(fmaxf(x1, 0.0f), maxx);
        y1 = fminf(fmaxf(y1, 0.0f), maxy);
        x2 = fminf(fmaxf(x2, 0.0f), maxx);
        y2 = fminf(fmaxf(y2, 0.0f), maxy);
        props[(size_t)b * PRE_K + r] = make_float4(x1, y1, x2, y2);
    }
}

// ---------------- NMS suppression bitmask ----------------
// grid (32 colBlocks, 32 rowBlocks, B), block 64
__global__ void mask_kernel(const float4* __restrict__ boxes,
                            unsigned long long* __restrict__ mask) {
    int colB = blockIdx.x, rowB = blockIdx.y, b = blockIdx.z;
    if (colB < rowB) return;
    __shared__ float4 cb[64];
    int t = threadIdx.x;
    int j0 = colB * 64;
    cb[t] = (j0 + t < PRE_K) ? boxes[(size_t)b * PRE_K + j0 + t] : make_float4(0.f, 0.f, -1.f, -1.f);
    __syncthreads();
    int i = rowB * 64 + t;
    if (i >= PRE_K) return;
    float4 mb = boxes[(size_t)b * PRE_K + i];
    float aarea = __fmul_rn(__fsub_rn(mb.z, mb.x), __fsub_rn(mb.w, mb.y));
    unsigned long long m = 0ULL;
    for (int jj = 0; jj < 64; ++jj) {
        int j = j0 + jj;
        if (j > i && j < PRE_K) {
            float4 c = cb[jj];
            float xx1 = fmaxf(mb.x, c.x), yy1 = fmaxf(mb.y, c.y);
            float xx2 = fminf(mb.z, c.z), yy2 = fminf(mb.w, c.w);
            float iw = fmaxf(__fsub_rn(xx2, xx1), 0.0f);
            float ih = fmaxf(__fsub_rn(yy2, yy1), 0.0f);
            float inter = __fmul_rn(iw, ih);
            float barea = __fmul_rn(__fsub_rn(c.z, c.x), __fsub_rn(c.w, c.y));
            float denom = __fadd_rn(__fsub_rn(__fadd_rn(aarea, barea), inter), 1e-9f);
            float iou = __fdiv_rn(inter, denom);
            if (iou > NMS_TH) m |= (1ULL << jj);
        }
    }
    mask[((size_t)(b * PRE_K + i)) * 32 + colB] = m;
}

// ---------------- serial greedy scan + output ----------------
#define CH 16
#define NCH (PRE_K / CH)  // 125

#define LOAD_CHUNK(BUF, C)                                               \
    _Pragma("unroll") for (int t = 0; t < CH; ++t) BUF[t] =              \
        act ? mrow[((size_t)((C) * CH + t)) * 32 + lane] : 0ULL;

#define PROCESS_CHUNK(BUF, CBASE)                                        \
    _Pragma("unroll") for (int t = 0; t < CH; ++t) {                     \
        int i = (CBASE) + t;                                             \
        int w = i >> 6;                                                  \
        unsigned long long rw = __shfl(remv, w, 64);                     \
        if (!((rw >> (i & 63)) & 1ULL)) {                                \
            if (lane == 0 && cnt < POST_K) keeplist[cnt] = i;            \
            cnt++;                                                       \
            if (lane >= w) remv |= BUF[t];                               \
        }                                                                \
    }

__global__ void scan_kernel(const unsigned long long* __restrict__ mask,
                            const float4* __restrict__ boxes,
                            float* __restrict__ out) {
    int b = blockIdx.x;
    int lane = threadIdx.x;
    const unsigned long long* mrow = mask + (size_t)b * PRE_K * 32;
    __shared__ int keeplist[POST_K];
    bool act = lane < 32;
    unsigned long long remv = 0ULL;
    int cnt = 0;
    unsigned long long bufA[CH], bufB[CH], bufC[CH];
    LOAD_CHUNK(bufA, 0)
    LOAD_CHUNK(bufB, 1)
    LOAD_CHUNK(bufC, 2)
    for (int c = 0; c < NCH; c += 3) {
        PROCESS_CHUNK(bufA, c * CH)
        if (cnt >= POST_K) break;
        if (c + 3 < NCH) { LOAD_CHUNK(bufA, c + 3) }
        if (c + 1 < NCH) {
            PROCESS_CHUNK(bufB, (c + 1) * CH)
            if (cnt >= POST_K) break;
            if (c + 4 < NCH) { LOAD_CHUNK(bufB, c + 4) }
        }
        if (c + 2 < NCH) {
            PROCESS_CHUNK(bufC, (c + 2) * CH)
            if (cnt >= POST_K) break;
            if (c + 5 < NCH) { LOAD_CHUNK(bufC, c + 5) }
        }
    }
    __syncthreads();
    int K = min(cnt, POST_K);
    const float4* bb = boxes + (size_t)b * PRE_K;
    for (int r = lane; r < POST_K; r += 64) {
        float4 v = make_float4(0.f, 0.f, 0.f, 0.f);
        if (r < K) v = bb[keeplist[r]];
        float* o = out + ((size_t)b * POST_K + r) * 5;
        o[0] = (float)b;
        o[1] = v.x;
        o[2] = v.y;
        o[3] = v.z;
        o[4] = v.w;
    }
}

// ---------------- launcher ----------------
extern "C" void kernel_launch(void* const* d_in, const int* in_sizes, int n_in,
                              void* d_out, int out_size, void* d_ws, size_t ws_size,
                              hipStream_t stream) {
    const float* scores = (const float*)d_in[0];
    const float* deltas = (const float*)d_in[1];
    const float* im_info = (const float*)d_in[2];
    float* out = (float*)d_out;
    char* ws = (char*)d_ws;

    // workspace layout (bytes)
    float4* props = (float4*)(ws + 0);                       // 8*2000*16 = 256000
    unsigned long long* mask = (unsigned long long*)(ws + 262144); // 8*2000*32*8 = 4096000
    // total ≈ 4.36 MB; no init needed (all consumed bytes are written first)

    hipLaunchKernelGGL(topk_kernel, dim3(NB), dim3(TPB), 0, stream,
                       scores, deltas, im_info, props);
    hipLaunchKernelGGL(mask_kernel, dim3(32, 32, NB), dim3(64), 0, stream, props, mask);
    hipLaunchKernelGGL(scan_kernel, dim3(NB), dim3(64), 0, stream, mask, props, out);
}